// Round 13
// baseline (3088.846 us; speedup 1.0000x reference)
//
#include <hip/hip_runtime.h>
#include <hip/hip_bf16.h>
#include <math.h>

#define HH 80
#define WW 80
#define NPIX 6400
#define LL 21
#define NITER 5
#define C_LOG2E 1.44269504088896f

// bilateral MFMA kernel geometry (R10-proven: SJ=320, 4 blocks/CU)
#define SJ  320             // j-slice per block
#define CHK (SJ / 32)       // 10 chunks of 32 j
#define QROW 164            // Q LDS row stride in u32 (320 bf16 + pad)
#define QROWS 22            // rows 0..20 labels, 21 = ones; lanes m>=22 alias row 0
#define NBLK 1000           // 50 x 20 tiles; <= 4/CU x 256 = 1024 (deadlock-safe)
#define NBY  20             // j0 slices (partial-accumulator count)
#define SPWORK (LL * NPIX)          // spat_x units (pixel-rows)
#define SYWORK ((LL + 1) * NPIX)    // spat_y + reduce units

typedef short short8 __attribute__((ext_vector_type(8)));
typedef float f32x16 __attribute__((ext_vector_type(16)));

__device__ inline ushort bf_rne(float x) {
    uint u = __float_as_uint(x);
    return (ushort)((u + 0x7FFFu + ((u >> 16) & 1u)) >> 16);
}
__device__ inline float bf_to_f(ushort h) { return __uint_as_float(((uint)h) << 16); }
// 1-op RTZ pack for E (per-j error cancels in the bi/norm ratio)
__device__ inline uint pk2z(float a, float b) {
    return __builtin_amdgcn_perm(__float_as_uint(b), __float_as_uint(a), 0x07060302u);
}
__device__ inline float fexp2(float x) { return __builtin_amdgcn_exp2f(x); }

// ================ setup: blocks 0..24 = pre+softmax0, block 25 = mats + ctr zero
__global__ void k_setup(const float* __restrict__ img, const float* __restrict__ unary,
                        const float* __restrict__ Wsp, const float* __restrict__ Wbi,
                        const float* __restrict__ C, ushort* __restrict__ fjg,
                        uint* __restrict__ fig, float* __restrict__ mhs,
                        float* __restrict__ nsp, float* __restrict__ q,
                        ushort* __restrict__ qb16, float* __restrict__ M1,
                        float* __restrict__ M2, uint* __restrict__ ctr) {
    int tid = threadIdx.x;
    if (blockIdx.x == 25) {           // ---- mats role + barrier-counter init
        if (tid < 16) ctr[tid] = 0u;  // counters MUST be 0 at mega-kernel start
        for (int t = tid; t < LL * LL; t += 256) {
            int l = t / LL, k = t % LL;
            float a = 0.f, b = 0.f;
            for (int m = 0; m < LL; m++) {
                a += C[l * LL + m] * Wsp[m * LL + k];
                b += C[l * LL + m] * Wbi[m * LL + k];
            }
            M1[t] = a; M2[t] = b;
        }
        return;
    }
    __shared__ float sxT[WW];
    if (tid < WW) {
        float s = 0.f;
        for (int t = 0; t < WW; t++) { float d = (float)(tid - t); s += __expf(-d * d * (1.0f / 18.0f)); }
        sxT[tid] = s;
    }
    __syncthreads();
    int i = blockIdx.x * 256 + tid;
    int x = i % WW, y = i / WW;
    float f[5];
    f[0] = (float)x * (1.0f / 160.0f);
    f[1] = (float)y * (1.0f / 160.0f);
    f[2] = (img[0 * NPIX + i] - 127.5f) * (1.0f / 3.0f);
    f[3] = (img[1 * NPIX + i] - 127.5f) * (1.0f / 3.0f);
    f[4] = (img[2 * NPIX + i] - 127.5f) * (1.0f / 3.0f);
    float s = 0.f;
    ushort hi[5], lo[5], Hi[5], Lo[5];
#pragma unroll
    for (int c = 0; c < 5; c++) {
        s += f[c] * f[c];
        hi[c] = bf_rne(f[c]);
        lo[c] = bf_rne(f[c] - bf_to_f(hi[c]));
        float a = C_LOG2E * f[c];
        Hi[c] = bf_rne(a);
        Lo[c] = bf_rne(a - bf_to_f(Hi[c]));
    }
    float mi = -0.5f * C_LOG2E * s;
    mhs[i] = mi;
    ushort mih = bf_rne(mi);
    ushort mil = bf_rne(mi - bf_to_f(mih));
    {   // A-side row: [h0..h4, l2,l3,l4, h2,h3,h4, l2,l3,l4, 1.0, 1.0]
        ushort r0[16] = { hi[0], hi[1], hi[2], hi[3], hi[4], lo[2], lo[3], lo[4],
                          hi[2], hi[3], hi[4], lo[2], lo[3], lo[4], 0x3F80, 0x3F80 };
        uint4 w0, w1;
        w0.x = (uint)r0[0] | ((uint)r0[1] << 16);  w0.y = (uint)r0[2] | ((uint)r0[3] << 16);
        w0.z = (uint)r0[4] | ((uint)r0[5] << 16);  w0.w = (uint)r0[6] | ((uint)r0[7] << 16);
        w1.x = (uint)r0[8] | ((uint)r0[9] << 16);  w1.y = (uint)r0[10] | ((uint)r0[11] << 16);
        w1.z = (uint)r0[12] | ((uint)r0[13] << 16); w1.w = (uint)r0[14] | ((uint)r0[15] << 16);
        *(uint4*)(fjg + (size_t)i * 16) = w0;
        *(uint4*)(fjg + (size_t)i * 16 + 8) = w1;
    }
    {   // B-side row: [H0..H4, H2,H3,H4, L2,L3,L4, L2,L3,L4, mih, mil]
        ushort r1[16] = { Hi[0], Hi[1], Hi[2], Hi[3], Hi[4], Hi[2], Hi[3], Hi[4],
                          Lo[2], Lo[3], Lo[4], Lo[2], Lo[3], Lo[4], mih, mil };
        uint4 w0, w1;
        w0.x = (uint)r1[0] | ((uint)r1[1] << 16);  w0.y = (uint)r1[2] | ((uint)r1[3] << 16);
        w0.z = (uint)r1[4] | ((uint)r1[5] << 16);  w0.w = (uint)r1[6] | ((uint)r1[7] << 16);
        w1.x = (uint)r1[8] | ((uint)r1[9] << 16);  w1.y = (uint)r1[10] | ((uint)r1[11] << 16);
        w1.z = (uint)r1[12] | ((uint)r1[13] << 16); w1.w = (uint)r1[14] | ((uint)r1[15] << 16);
        *(uint4*)(fig + (size_t)i * 8) = w0;
        *(uint4*)(fig + (size_t)i * 8 + 4) = w1;
    }
    nsp[i] = 1.0f / (sxT[x] * sxT[y] + 1e-8f);
    float v[LL];
    float mx = -1e30f;
    for (int l = 0; l < LL; l++) { v[l] = unary[l * NPIX + i]; mx = fmaxf(mx, v[l]); }
    float ss = 0.f;
    for (int l = 0; l < LL; l++) { v[l] = __expf(v[l] - mx); ss += v[l]; }
    float r = 1.0f / ss;
    for (int l = 0; l < LL; l++) {
        float qv = v[l] * r;
        q[l * NPIX + i] = qv;
        qb16[(size_t)l * NPIX + i] = bf_rne(qv);
    }
}

// device-scope barrier: all NBLK blocks are co-resident (grid <= capacity).
// Counter pre-zeroed by k_setup. Bounded spin -> a bug shows as absmax fail.
__device__ inline void gbar(uint* c) {
    __syncthreads();                  // all waves' prior stores drained to L2
    if (threadIdx.x == 0) {
        __threadfence();              // release: L2 writeback to device scope
        __hip_atomic_fetch_add(c, 1u, __ATOMIC_RELEASE, __HIP_MEMORY_SCOPE_AGENT);
        uint v = 0; int g = 0;
        for (;;) {
            v = __hip_atomic_load(c, __ATOMIC_ACQUIRE, __HIP_MEMORY_SCOPE_AGENT);
            if (v >= NBLK) break;
            if (++g > 2000000) break;     // bailout: fail visibly, don't hang
            __builtin_amdgcn_s_sleep(8);
        }
        __threadfence();              // acquire: invalidate stale cached lines
    }
    __syncthreads();
}

__device__ inline f32x16 ldmhs(const float* p, int h) {
    float4 a0 = *(const float4*)(p + 8 * h);
    float4 a1 = *(const float4*)(p + 8 * h + 4);
    float4 a2 = *(const float4*)(p + 16 + 8 * h);
    float4 a3 = *(const float4*)(p + 16 + 8 * h + 4);
    f32x16 cv;
    cv[0] = a0.x;  cv[1] = a0.y;  cv[2] = a0.z;  cv[3] = a0.w;
    cv[4] = a1.x;  cv[5] = a1.y;  cv[6] = a1.z;  cv[7] = a1.w;
    cv[8] = a2.x;  cv[9] = a2.y;  cv[10] = a2.z; cv[11] = a2.w;
    cv[12] = a3.x; cv[13] = a3.y; cv[14] = a3.z; cv[15] = a3.w;
    return cv;
}

// ================ persistent mega-kernel: all 5 iterations, 14 barriers
__global__ __launch_bounds__(256, 4)
void k_mega(const float* __restrict__ mhs, const ushort* __restrict__ fjg,
            const uint* __restrict__ fig, float* __restrict__ q,
            ushort* __restrict__ qb16, float* __restrict__ bip,
            float* __restrict__ tmpx, float* __restrict__ sp,
            float* __restrict__ bi, const float* __restrict__ nsp,
            const float* __restrict__ unary, const float* __restrict__ M1,
            const float* __restrict__ M2, float* __restrict__ out,
            uint* __restrict__ ctr) {
    __shared__ __align__(16) uint  FjL[SJ * 12];
    __shared__ __align__(16) float mhsL[SJ];
    __shared__ __align__(16) uint  QL[QROWS * QROW];
    __shared__ float gT[WW];
    __shared__ float m1s[LL * 24];
    __shared__ float m2s[LL * 24];
    int tid = threadIdx.x;
    int bid = blockIdx.x;
    int bx = bid % 50, by = bid / 50;
    int j0 = by * SJ;
    // ---- one-time staging (constant across iterations)
    for (int idx = tid; idx < SJ * 2; idx += 256) {
        int r = idx >> 1, hf = idx & 1;
        uint4 v = ((const uint4*)(fjg + (size_t)(j0 + r) * 16))[hf];
        *(uint4*)&FjL[r * 12 + hf * 4] = v;
    }
    for (int idx = tid; idx < SJ; idx += 256) mhsL[idx] = mhs[j0 + idx];
    if (tid < WW) gT[tid] = __expf(-(float)(tid * tid) * (1.0f / 18.0f));
    for (int t = tid; t < LL * LL; t += 256) {
        int l = t / LL, k = t % LL;
        m1s[l * 24 + k] = M1[t];
        m2s[l * 24 + k] = M2[t];
    }
    int lane = tid & 63, wid = tid >> 6;
    int h = lane >> 5, m = lane & 31;
    int i = bx * 128 + wid * 32 + m;
    union U8 { uint u[4]; short8 s; };
    U8 bfr;
    {
        uint4 bv = *(const uint4*)(fig + (size_t)i * 8 + h * 4);
        bfr.u[0] = bv.x; bfr.u[1] = bv.y; bfr.u[2] = bv.z; bfr.u[3] = bv.w;
    }
    int jrow = (m & ~12) | ((m & 4) << 1) | ((m & 8) >> 1);
    int qrow = (m < QROWS) ? m : 0;
    const uint* qbase = &QL[qrow * QROW + h * 4];

    for (int it = 0; it < NITER; it++) {
        // ---- stage Q (bf16 in global) as [22 l-rows][SJ j]; row 21 = ones
        for (int idx = tid; idx < QROWS * (SJ / 2); idx += 256) {
            int l = idx / (SJ / 2), jp = idx % (SJ / 2);
            uint v;
            if (l < LL) {
                const uint* p = (const uint*)qb16 + (((size_t)l * NPIX + j0) >> 1);
                v = p[jp];
            } else {
                v = 0x3F803F80u;
            }
            QL[l * QROW + jp] = v;
        }
        __syncthreads();
        // ---- P1: bilateral MFMA tile
        f32x16 acc;
#pragma unroll
        for (int k = 0; k < 16; k++) acc[k] = 0.f;
        for (int c = 0; c < CHK; c++) {
            int jb = c * 32;
            f32x16 cv = ldmhs(&mhsL[jb], h);
            short8 af = *(const short8*)&FjL[(jb + jrow) * 12 + h * 4];
            f32x16 d1 = __builtin_amdgcn_mfma_f32_32x32x16_bf16(af, bfr.s, cv, 0, 0, 0);
            short8 qa = *(const short8*)(qbase + c * 16);
            short8 qb = *(const short8*)(qbase + c * 16 + 8);
            U8 ea;
            ea.u[0] = pk2z(fexp2(d1[0]), fexp2(d1[1]));
            ea.u[1] = pk2z(fexp2(d1[2]), fexp2(d1[3]));
            ea.u[2] = pk2z(fexp2(d1[4]), fexp2(d1[5]));
            ea.u[3] = pk2z(fexp2(d1[6]), fexp2(d1[7]));
            acc = __builtin_amdgcn_mfma_f32_32x32x16_bf16(qa, ea.s, acc, 0, 0, 0);
            U8 eb;
            eb.u[0] = pk2z(fexp2(d1[8]),  fexp2(d1[9]));
            eb.u[1] = pk2z(fexp2(d1[10]), fexp2(d1[11]));
            eb.u[2] = pk2z(fexp2(d1[12]), fexp2(d1[13]));
            eb.u[3] = pk2z(fexp2(d1[14]), fexp2(d1[15]));
            acc = __builtin_amdgcn_mfma_f32_32x32x16_bf16(qb, eb.s, acc, 0, 0, 0);
        }
#pragma unroll
        for (int r = 0; r < 16; r++) {
            int l = (r & 3) + 8 * (r >> 2) + 4 * h;
            if (l < LL + 1) bip[((size_t)by * (LL + 1) + l) * NPIX + i] = acc[r];
        }
        // ---- spat_x rider: uniform ~134-px slice
        {
            int start = (int)(((long)bid * SPWORK) / NBLK);
            int end   = (int)(((long)(bid + 1) * SPWORK) / NBLK);
            int cnt = end - start;
            if (tid < cnt) {
                int fidx = start + tid;
                int l = fidx / NPIX;
                int p = fidx - l * NPIX;
                int x = p % WW, y = p / WW;
                const float* rowq = q + (size_t)l * NPIX + y * WW;
                float s = 0.f;
                for (int xp = 0; xp < WW; xp++) {
                    int d = x - xp; d = d < 0 ? -d : d;
                    s += gT[d] * rowq[xp];
                }
                tmpx[(size_t)l * NPIX + p] = s;
            }
        }
        gbar(&ctr[3 * it]);
        // ---- P2: spat_y (l<21) + bilat partial reduce (all 22 rows)
        {
            int s = (int)(((long)bid * SYWORK) / NBLK);
            int e = (int)(((long)(bid + 1) * SYWORK) / NBLK);
            int cnt = e - s;                  // 140 or 141
            if (tid < cnt) {
                int u = s + tid;
                int l = u / NPIX;
                int px = u - l * NPIX;
                if (l < LL) {
                    int x = px % WW, y = px / WW;
                    const float* base = tmpx + (size_t)l * NPIX + x;
                    float s1 = 0.f;
                    for (int yp = 0; yp < HH; yp++) {
                        int d = y - yp; d = d < 0 ? -d : d;
                        s1 += gT[d] * base[yp * WW];
                    }
                    sp[(size_t)l * NPIX + px] = s1;
                }
                float s2 = 0.f;
                const float* p = bip + (size_t)l * NPIX + px;
#pragma unroll
                for (int byi = 0; byi < NBY; byi++)
                    s2 += p[(size_t)byi * (LL + 1) * NPIX];
                bi[(size_t)l * NPIX + px] = s2;
            }
        }
        gbar(&ctr[3 * it + 1]);
        // ---- P3: combine (+ softmax -> q, qb16 unless last)
        {
            int s = (bid * NPIX) / NBLK;
            int e = ((bid + 1) * NPIX) / NBLK;
            int cnt = e - s;                  // 6 or 7
            if (tid < cnt) {
                int ii = s + tid;
                float ns = nsp[ii];
                float nb = 1.0f / (bi[(size_t)LL * NPIX + ii] + 1e-8f);
                float sv[LL], bv[LL];
#pragma unroll
                for (int k = 0; k < LL; k++) {
                    sv[k] = sp[(size_t)k * NPIX + ii] * ns;
                    bv[k] = bi[(size_t)k * NPIX + ii] * nb;
                }
                float a[LL];
                for (int l = 0; l < LL; l++) {
                    float accv = unary[l * NPIX + ii];
                    const float* r1 = &m1s[l * 24];
                    const float* r2 = &m2s[l * 24];
#pragma unroll
                    for (int k = 0; k < LL; k++) accv += r1[k] * sv[k] + r2[k] * bv[k];
                    a[l] = accv;
                }
                if (it == NITER - 1) {
                    for (int l = 0; l < LL; l++) out[l * NPIX + ii] = a[l];
                } else {
                    float mx = -1e30f;
                    for (int l = 0; l < LL; l++) mx = fmaxf(mx, a[l]);
                    float ssum = 0.f;
                    for (int l = 0; l < LL; l++) { a[l] = __expf(a[l] - mx); ssum += a[l]; }
                    float r = 1.0f / ssum;
                    for (int l = 0; l < LL; l++) {
                        float qv = a[l] * r;
                        q[l * NPIX + ii] = qv;
                        qb16[(size_t)l * NPIX + ii] = bf_rne(qv);
                    }
                }
            }
        }
        if (it < NITER - 1) gbar(&ctr[3 * it + 2]);
    }
}

extern "C" void kernel_launch(void* const* d_in, const int* in_sizes, int n_in,
                              void* d_out, int out_size, void* d_ws, size_t ws_size,
                              hipStream_t stream) {
    const float* img   = (const float*)d_in[0];
    const float* unary = (const float*)d_in[1];
    const float* Wsp   = (const float*)d_in[2];
    const float* Wbi   = (const float*)d_in[3];
    const float* C     = (const float*)d_in[4];
    float* out = (float*)d_out;

    const int LN = LL * NPIX;
    float* w = (float*)d_ws;
    float*  q    = w;  w += LN;
    float*  tmpx = w;  w += LN;
    float*  sp   = w;  w += LN;
    float*  bi   = w;  w += (LL + 1) * NPIX;          // 21 msg + 1 norm
    float*  bip  = w;  w += NBY * (LL + 1) * NPIX;    // per-j0-slice partials
    float*  mhs  = w;  w += NPIX;
    float*  nsp  = w;  w += NPIX;
    ushort* fjg  = (ushort*)w;  w += 8 * NPIX;        // A-rows [N][16 bf16]
    uint*   fig  = (uint*)w;    w += 8 * NPIX;        // B-rows [N][8 u32]
    ushort* qb16 = (ushort*)w;  w += (LN + 1) / 2;    // Q in bf16 [21][N]
    float*  M1   = w;  w += LL * LL;
    float*  M2   = w;  w += LL * LL;
    uint*   ctr  = (uint*)w;    w += 16;              // barrier counters

    k_setup<<<26, 256, 0, stream>>>(img, unary, Wsp, Wbi, C, fjg, fig, mhs, nsp,
                                    q, qb16, M1, M2, ctr);
    k_mega<<<NBLK, 256, 0, stream>>>(mhs, fjg, fig, q, qb16, bip, tmpx, sp, bi,
                                     nsp, unary, M1, M2, out, ctr);
}

// Round 14
// 213.008 us; speedup vs baseline: 14.5010x; 14.5010x over previous
//
#include <hip/hip_runtime.h>
#include <hip/hip_bf16.h>
#include <math.h>

#define HH 80
#define WW 80
#define NPIX 6400
#define LL 21
#define NITER 5
#define C_LOG2E 1.44269504088896f

// bilateral MFMA kernel geometry (R10-proven: SJ=320, 4 blocks/CU, 1000 blocks)
#define SJ  320             // j-slice per block
#define CHK (SJ / 32)       // 10 chunks of 32 j
#define QROW 164            // Q LDS row stride in u32 (320 bf16 + pad)
#define QROWS 22            // rows 0..20 labels, 21 = ones; lanes m>=22 alias row 0
#define NBLK 1000           // 50 x 20 tiles == one co-residency round at 4/CU
#define NBY  20             // j0 slices (partial-accumulator count)
#define SPWORK (LL * NPIX)  // 134400 spat_x pixel-rows, uniform over blocks

// merged spat_y+reduce+combine kernel geometry
#define PXB 16              // pixels per block
#define SYB (NPIX / PXB)    // 400 blocks (R8-proven scale)
#define SYT 384             // 6 waves; 352 phase-A tasks -> 1/thread

typedef short short8 __attribute__((ext_vector_type(8)));
typedef float f32x16 __attribute__((ext_vector_type(16)));

__device__ inline ushort bf_rne(float x) {
    uint u = __float_as_uint(x);
    return (ushort)((u + 0x7FFFu + ((u >> 16) & 1u)) >> 16);
}
__device__ inline float bf_to_f(ushort h) { return __uint_as_float(((uint)h) << 16); }
// 1-op RTZ pack for E (per-j error cancels in the bi/norm ratio)
__device__ inline uint pk2z(float a, float b) {
    return __builtin_amdgcn_perm(__float_as_uint(b), __float_as_uint(a), 0x07060302u);
}
__device__ inline float fexp2(float x) { return __builtin_amdgcn_exp2f(x); }

// ================ setup: blocks 0..24 = pre+softmax0, block 25 = mats
__global__ void k_setup(const float* __restrict__ img, const float* __restrict__ unary,
                        const float* __restrict__ Wsp, const float* __restrict__ Wbi,
                        const float* __restrict__ C, ushort* __restrict__ fjg,
                        uint* __restrict__ fig, float* __restrict__ mhs,
                        float* __restrict__ nsp, ushort* __restrict__ qb16,
                        float* __restrict__ M1, float* __restrict__ M2) {
    int tid = threadIdx.x;
    if (blockIdx.x == 25) {           // ---- mats role
        for (int t = tid; t < LL * LL; t += 256) {
            int l = t / LL, k = t % LL;
            float a = 0.f, b = 0.f;
            for (int m = 0; m < LL; m++) {
                a += C[l * LL + m] * Wsp[m * LL + k];
                b += C[l * LL + m] * Wbi[m * LL + k];
            }
            M1[t] = a; M2[t] = b;
        }
        return;
    }
    __shared__ float sxT[WW];
    if (tid < WW) {
        float s = 0.f;
        for (int t = 0; t < WW; t++) { float d = (float)(tid - t); s += __expf(-d * d * (1.0f / 18.0f)); }
        sxT[tid] = s;
    }
    __syncthreads();
    int i = blockIdx.x * 256 + tid;
    int x = i % WW, y = i / WW;
    float f[5];
    f[0] = (float)x * (1.0f / 160.0f);
    f[1] = (float)y * (1.0f / 160.0f);
    f[2] = (img[0 * NPIX + i] - 127.5f) * (1.0f / 3.0f);
    f[3] = (img[1 * NPIX + i] - 127.5f) * (1.0f / 3.0f);
    f[4] = (img[2 * NPIX + i] - 127.5f) * (1.0f / 3.0f);
    float s = 0.f;
    ushort hi[5], lo[5], Hi[5], Lo[5];
#pragma unroll
    for (int c = 0; c < 5; c++) {
        s += f[c] * f[c];
        hi[c] = bf_rne(f[c]);
        lo[c] = bf_rne(f[c] - bf_to_f(hi[c]));
        float a = C_LOG2E * f[c];
        Hi[c] = bf_rne(a);
        Lo[c] = bf_rne(a - bf_to_f(Hi[c]));
    }
    float mi = -0.5f * C_LOG2E * s;
    mhs[i] = mi;
    ushort mih = bf_rne(mi);
    ushort mil = bf_rne(mi - bf_to_f(mih));
    {   // A-side row: [h0..h4, l2,l3,l4, h2,h3,h4, l2,l3,l4, 1.0, 1.0]
        ushort r0[16] = { hi[0], hi[1], hi[2], hi[3], hi[4], lo[2], lo[3], lo[4],
                          hi[2], hi[3], hi[4], lo[2], lo[3], lo[4], 0x3F80, 0x3F80 };
        uint4 w0, w1;
        w0.x = (uint)r0[0] | ((uint)r0[1] << 16);  w0.y = (uint)r0[2] | ((uint)r0[3] << 16);
        w0.z = (uint)r0[4] | ((uint)r0[5] << 16);  w0.w = (uint)r0[6] | ((uint)r0[7] << 16);
        w1.x = (uint)r0[8] | ((uint)r0[9] << 16);  w1.y = (uint)r0[10] | ((uint)r0[11] << 16);
        w1.z = (uint)r0[12] | ((uint)r0[13] << 16); w1.w = (uint)r0[14] | ((uint)r0[15] << 16);
        *(uint4*)(fjg + (size_t)i * 16) = w0;
        *(uint4*)(fjg + (size_t)i * 16 + 8) = w1;
    }
    {   // B-side row: [H0..H4, H2,H3,H4, L2,L3,L4, L2,L3,L4, mih, mil]
        ushort r1[16] = { Hi[0], Hi[1], Hi[2], Hi[3], Hi[4], Hi[2], Hi[3], Hi[4],
                          Lo[2], Lo[3], Lo[4], Lo[2], Lo[3], Lo[4], mih, mil };
        uint4 w0, w1;
        w0.x = (uint)r1[0] | ((uint)r1[1] << 16);  w0.y = (uint)r1[2] | ((uint)r1[3] << 16);
        w0.z = (uint)r1[4] | ((uint)r1[5] << 16);  w0.w = (uint)r1[6] | ((uint)r1[7] << 16);
        w1.x = (uint)r1[8] | ((uint)r1[9] << 16);  w1.y = (uint)r1[10] | ((uint)r1[11] << 16);
        w1.z = (uint)r1[12] | ((uint)r1[13] << 16); w1.w = (uint)r1[14] | ((uint)r1[15] << 16);
        *(uint4*)(fig + (size_t)i * 8) = w0;
        *(uint4*)(fig + (size_t)i * 8 + 4) = w1;
    }
    nsp[i] = 1.0f / (sxT[x] * sxT[y] + 1e-8f);
    float v[LL];
    float mx = -1e30f;
    for (int l = 0; l < LL; l++) { v[l] = unary[l * NPIX + i]; mx = fmaxf(mx, v[l]); }
    float ss = 0.f;
    for (int l = 0; l < LL; l++) { v[l] = __expf(v[l] - mx); ss += v[l]; }
    float r = 1.0f / ss;
    for (int l = 0; l < LL; l++) qb16[(size_t)l * NPIX + i] = bf_rne(v[l] * r);
}

__device__ inline f32x16 ldmhs(const float* p, int h) {
    float4 a0 = *(const float4*)(p + 8 * h);
    float4 a1 = *(const float4*)(p + 8 * h + 4);
    float4 a2 = *(const float4*)(p + 16 + 8 * h);
    float4 a3 = *(const float4*)(p + 16 + 8 * h + 4);
    f32x16 cv;
    cv[0] = a0.x;  cv[1] = a0.y;  cv[2] = a0.z;  cv[3] = a0.w;
    cv[4] = a1.x;  cv[5] = a1.y;  cv[6] = a1.z;  cv[7] = a1.w;
    cv[8] = a2.x;  cv[9] = a2.y;  cv[10] = a2.z; cv[11] = a2.w;
    cv[12] = a3.x; cv[13] = a3.y; cv[14] = a3.z; cv[15] = a3.w;
    return cv;
}

// ================ iteration kernel 1: 1000 blocks, one co-residency round.
// All blocks: bilat MFMA tile; uniform ~134-px spat_x rider (reads qb16).
__global__ __launch_bounds__(256, 4)
void k_iter1(const float* __restrict__ mhs, const ushort* __restrict__ fjg,
             const uint* __restrict__ fig, const ushort* __restrict__ qb16,
             float* __restrict__ bip, float* __restrict__ tmpx) {
    __shared__ __align__(16) uint  FjL[SJ * 12];
    __shared__ __align__(16) float mhsL[SJ];
    __shared__ __align__(16) uint  QL[QROWS * QROW];
    __shared__ float gT[WW];
    int tid = threadIdx.x;
    int bid = blockIdx.x;
    int bx = bid % 50, by = bid / 50;
    int j0 = by * SJ;
    for (int idx = tid; idx < SJ * 2; idx += 256) {
        int r = idx >> 1, hf = idx & 1;
        uint4 v = ((const uint4*)(fjg + (size_t)(j0 + r) * 16))[hf];
        *(uint4*)&FjL[r * 12 + hf * 4] = v;
    }
    for (int idx = tid; idx < SJ; idx += 256) mhsL[idx] = mhs[j0 + idx];
    if (tid < WW) gT[tid] = __expf(-(float)(tid * tid) * (1.0f / 18.0f));
    // ---- stage Q (bf16 in global) as [22 l-rows][SJ j]; row 21 = ones
    for (int idx = tid; idx < QROWS * (SJ / 2); idx += 256) {
        int l = idx / (SJ / 2), jp = idx % (SJ / 2);
        uint v;
        if (l < LL) {
            const uint* p = (const uint*)qb16 + (((size_t)l * NPIX + j0) >> 1);
            v = p[jp];
        } else {
            v = 0x3F803F80u;
        }
        QL[l * QROW + jp] = v;
    }
    int lane = tid & 63, wid = tid >> 6;
    int h = lane >> 5, m = lane & 31;
    int i = bx * 128 + wid * 32 + m;
    union U8 { uint u[4]; short8 s; };
    U8 bfr;
    {
        uint4 bv = *(const uint4*)(fig + (size_t)i * 8 + h * 4);
        bfr.u[0] = bv.x; bfr.u[1] = bv.y; bfr.u[2] = bv.z; bfr.u[3] = bv.w;
    }
    int jrow = (m & ~12) | ((m & 4) << 1) | ((m & 8) >> 1);
    int qrow = (m < QROWS) ? m : 0;
    __syncthreads();
    f32x16 acc;
#pragma unroll
    for (int k = 0; k < 16; k++) acc[k] = 0.f;
    const uint* qbase = &QL[qrow * QROW + h * 4];
    for (int c = 0; c < CHK; c++) {
        int jb = c * 32;
        f32x16 cv = ldmhs(&mhsL[jb], h);
        short8 af = *(const short8*)&FjL[(jb + jrow) * 12 + h * 4];
        f32x16 d1 = __builtin_amdgcn_mfma_f32_32x32x16_bf16(af, bfr.s, cv, 0, 0, 0);
        short8 qa = *(const short8*)(qbase + c * 16);
        short8 qb = *(const short8*)(qbase + c * 16 + 8);
        U8 ea;
        ea.u[0] = pk2z(fexp2(d1[0]), fexp2(d1[1]));
        ea.u[1] = pk2z(fexp2(d1[2]), fexp2(d1[3]));
        ea.u[2] = pk2z(fexp2(d1[4]), fexp2(d1[5]));
        ea.u[3] = pk2z(fexp2(d1[6]), fexp2(d1[7]));
        acc = __builtin_amdgcn_mfma_f32_32x32x16_bf16(qa, ea.s, acc, 0, 0, 0);
        U8 eb;
        eb.u[0] = pk2z(fexp2(d1[8]),  fexp2(d1[9]));
        eb.u[1] = pk2z(fexp2(d1[10]), fexp2(d1[11]));
        eb.u[2] = pk2z(fexp2(d1[12]), fexp2(d1[13]));
        eb.u[3] = pk2z(fexp2(d1[14]), fexp2(d1[15]));
        acc = __builtin_amdgcn_mfma_f32_32x32x16_bf16(qb, eb.s, acc, 0, 0, 0);
    }
#pragma unroll
    for (int r = 0; r < 16; r++) {
        int l = (r & 3) + 8 * (r >> 2) + 4 * h;
        if (l < LL + 1) bip[((size_t)by * (LL + 1) + l) * NPIX + i] = acc[r];
    }
    // ---- spat_x rider: uniform ~134-px slice; reads bf16 Q
    {
        int start = (int)(((long)bid * SPWORK) / NBLK);
        int end   = (int)(((long)(bid + 1) * SPWORK) / NBLK);
        int cnt = end - start;
        if (tid < cnt) {
            int fidx = start + tid;
            int l = fidx / NPIX;
            int p = fidx - l * NPIX;
            int x = p % WW, y = p / WW;
            const ushort* rowq = qb16 + (size_t)l * NPIX + y * WW;
            float s = 0.f;
            for (int xp = 0; xp < WW; xp++) {
                int d = x - xp; d = d < 0 ? -d : d;
                s += gT[d] * bf_to_f(rowq[xp]);
            }
            tmpx[(size_t)l * NPIX + p] = s;
        }
    }
}

// ================ iteration kernel 2 (merged): spat_y + reduce + combine + softmax
// 400 blocks x 384 thr; block owns ALL 22 rows of its 16 pixels -> no global
// sp/bi round-trip, no extra dispatch. Phase A: 352 tasks, 1/thread.
__global__ __launch_bounds__(SYT)
void k_syc(const float* __restrict__ unary, const float* __restrict__ tmpx,
           const float* __restrict__ bip, const float* __restrict__ nsp,
           const float* __restrict__ M1, const float* __restrict__ M2,
           ushort* __restrict__ qb16, float* __restrict__ out, int last) {
    __shared__ float m1s[LL * 24];
    __shared__ float m2s[LL * 24];
    __shared__ float gT[HH];
    __shared__ float svL[PXB][QROWS];   // [pxl][l] spatial (l<21)
    __shared__ float bvL[PXB][QROWS];   // [pxl][l] bilat reduce (l<=21)
    __shared__ float aex[PXB][QROWS];   // [pxl][l] combined logits
    int tid = threadIdx.x;
    int px0 = blockIdx.x * PXB;
    for (int t = tid; t < LL * LL; t += SYT) {
        int l = t / LL, k = t % LL;
        m1s[l * 24 + k] = M1[t];
        m2s[l * 24 + k] = M2[t];
    }
    if (tid < HH) gT[tid] = __expf(-(float)(tid * tid) * (1.0f / 18.0f));
    __syncthreads();
    // ---- phase A: per (pixel, row): spat_y conv (l<21) + 20-slice bip reduce
    if (tid < PXB * QROWS) {
        int pxl = tid & (PXB - 1);
        int l = tid >> 4;
        int px = px0 + pxl;
        int x = px % WW, y = px / WW;
        if (l < LL) {
            const float* base = tmpx + (size_t)l * NPIX + x;
            float s1 = 0.f;
            for (int yp = 0; yp < HH; yp++) {
                int d = y - yp; d = d < 0 ? -d : d;
                s1 += gT[d] * base[yp * WW];
            }
            svL[pxl][l] = s1;
        }
        float s2 = 0.f;
        const float* p = bip + (size_t)l * NPIX + px;
#pragma unroll
        for (int byi = 0; byi < NBY; byi++)
            s2 += p[(size_t)byi * (LL + 1) * NPIX];
        bvL[pxl][l] = s2;
    }
    __syncthreads();
    // ---- phase B1: combine  a[l] = unary + ns*(M1.sv) + nb*(M2.bv)
    if (tid < PXB * LL + PXB) { }     // (no-op; keeps structure clear)
    if (tid < PXB * LL) {
        int pxl = tid & (PXB - 1);
        int l = tid >> 4;             // 0..20
        int px = px0 + pxl;
        float ns = nsp[px];
        float nb = 1.0f / (bvL[pxl][LL] + 1e-8f);
        float s1 = 0.f, s2 = 0.f;
        const float* r1 = &m1s[l * 24];
        const float* r2 = &m2s[l * 24];
#pragma unroll
        for (int k = 0; k < LL; k++) {
            s1 = fmaf(r1[k], svL[pxl][k], s1);
            s2 = fmaf(r2[k], bvL[pxl][k], s2);
        }
        float a = unary[l * NPIX + px] + ns * s1 + nb * s2;
        if (last) out[(size_t)l * NPIX + px] = a;
        else      aex[pxl][l] = a;
    }
    if (last) return;
    __syncthreads();
    // ---- phase B2: per-pixel softmax -> qb16
    if (tid < PXB) {
        int px = px0 + tid;
        float mx = -1e30f;
        for (int l = 0; l < LL; l++) mx = fmaxf(mx, aex[tid][l]);
        float s = 0.f;
        float e[LL];
        for (int l = 0; l < LL; l++) { e[l] = __expf(aex[tid][l] - mx); s += e[l]; }
        float r = 1.0f / s;
        for (int l = 0; l < LL; l++)
            qb16[(size_t)l * NPIX + px] = bf_rne(e[l] * r);
    }
}

extern "C" void kernel_launch(void* const* d_in, const int* in_sizes, int n_in,
                              void* d_out, int out_size, void* d_ws, size_t ws_size,
                              hipStream_t stream) {
    const float* img   = (const float*)d_in[0];
    const float* unary = (const float*)d_in[1];
    const float* Wsp   = (const float*)d_in[2];
    const float* Wbi   = (const float*)d_in[3];
    const float* C     = (const float*)d_in[4];
    float* out = (float*)d_out;

    const int LN = LL * NPIX;
    float* w = (float*)d_ws;
    float*  tmpx = w;  w += LN;
    float*  bip  = w;  w += NBY * (LL + 1) * NPIX;    // per-j0-slice partials
    float*  mhs  = w;  w += NPIX;
    float*  nsp  = w;  w += NPIX;
    ushort* fjg  = (ushort*)w;  w += 8 * NPIX;        // A-rows [N][16 bf16]
    uint*   fig  = (uint*)w;    w += 8 * NPIX;        // B-rows [N][8 u32]
    ushort* qb16 = (ushort*)w;  w += (LN + 1) / 2;    // Q in bf16 [21][N]
    float*  M1   = w;  w += LL * LL;
    float*  M2   = w;  w += LL * LL;

    k_setup<<<26, 256, 0, stream>>>(img, unary, Wsp, Wbi, C, fjg, fig, mhs, nsp,
                                    qb16, M1, M2);
    for (int it = 0; it < NITER; it++) {
        int last = (it == NITER - 1);
        k_iter1<<<NBLK, 256, 0, stream>>>(mhs, fjg, fig, qb16, bip, tmpx);
        k_syc<<<SYB, SYT, 0, stream>>>(unary, tmpx, bip, nsp, M1, M2, qb16, out, last);
    }
}

// Round 15
// 190.215 us; speedup vs baseline: 16.2387x; 1.1198x over previous
//
#include <hip/hip_runtime.h>
#include <hip/hip_bf16.h>
#include <math.h>

#define HH 80
#define WW 80
#define NPIX 6400
#define LL 21
#define NITER 5
#define C_LOG2E 1.44269504088896f

// bilateral MFMA kernel geometry (R10-proven: SJ=320, 4 blocks/CU, 1000 blocks)
#define SJ  320             // j-slice per block
#define CHK (SJ / 32)       // 10 chunks of 32 j
#define QROW 164            // Q LDS row stride in u32 (320 bf16 + pad)
#define QROWS 22            // rows 0..20 labels, 21 = ones; lanes m>=22 alias row 0
#define NBLK 1000           // 50 x 20 tiles == one co-residency round at 4/CU
#define NBY  20             // j0 slices (partial-accumulator count)
#define NLP  11             // packed row-pairs (22 rows -> 11 u32 rows)
#define SPWORK (LL * NPIX)  // 134400 spat_x pixel-rows, uniform over blocks

// merged spat_y+reduce+combine kernel geometry
#define PXB 16              // pixels per block
#define SYB (NPIX / PXB)    // 400 blocks (R8-proven scale)
#define SYT 384             // 6 waves

typedef short short8 __attribute__((ext_vector_type(8)));
typedef float f32x16 __attribute__((ext_vector_type(16)));

__device__ inline ushort bf_rne(float x) {
    uint u = __float_as_uint(x);
    return (ushort)((u + 0x7FFFu + ((u >> 16) & 1u)) >> 16);
}
__device__ inline float bf_to_f(ushort h) { return __uint_as_float(((uint)h) << 16); }
__device__ inline uint pk2(float a, float b) {
    __hip_bfloat162 t = __float22bfloat162_rn(make_float2(a, b));
    return *reinterpret_cast<uint*>(&t);
}
// 1-op RTZ pack for E (per-j error cancels in the bi/norm ratio)
__device__ inline uint pk2z(float a, float b) {
    return __builtin_amdgcn_perm(__float_as_uint(b), __float_as_uint(a), 0x07060302u);
}
__device__ inline float fexp2(float x) { return __builtin_amdgcn_exp2f(x); }

// ================ setup: blocks 0..24 = pre+softmax0, block 25 = mats
__global__ void k_setup(const float* __restrict__ img, const float* __restrict__ unary,
                        const float* __restrict__ Wsp, const float* __restrict__ Wbi,
                        const float* __restrict__ C, ushort* __restrict__ fjg,
                        uint* __restrict__ fig, float* __restrict__ mhs,
                        float* __restrict__ nsp, ushort* __restrict__ qb16,
                        float* __restrict__ M1, float* __restrict__ M2) {
    int tid = threadIdx.x;
    if (blockIdx.x == 25) {           // ---- mats role
        for (int t = tid; t < LL * LL; t += 256) {
            int l = t / LL, k = t % LL;
            float a = 0.f, b = 0.f;
            for (int m = 0; m < LL; m++) {
                a += C[l * LL + m] * Wsp[m * LL + k];
                b += C[l * LL + m] * Wbi[m * LL + k];
            }
            M1[t] = a; M2[t] = b;
        }
        return;
    }
    __shared__ float sxT[WW];
    if (tid < WW) {
        float s = 0.f;
        for (int t = 0; t < WW; t++) { float d = (float)(tid - t); s += __expf(-d * d * (1.0f / 18.0f)); }
        sxT[tid] = s;
    }
    __syncthreads();
    int i = blockIdx.x * 256 + tid;
    int x = i % WW, y = i / WW;
    float f[5];
    f[0] = (float)x * (1.0f / 160.0f);
    f[1] = (float)y * (1.0f / 160.0f);
    f[2] = (img[0 * NPIX + i] - 127.5f) * (1.0f / 3.0f);
    f[3] = (img[1 * NPIX + i] - 127.5f) * (1.0f / 3.0f);
    f[4] = (img[2 * NPIX + i] - 127.5f) * (1.0f / 3.0f);
    float s = 0.f;
    ushort hi[5], lo[5], Hi[5], Lo[5];
#pragma unroll
    for (int c = 0; c < 5; c++) {
        s += f[c] * f[c];
        hi[c] = bf_rne(f[c]);
        lo[c] = bf_rne(f[c] - bf_to_f(hi[c]));
        float a = C_LOG2E * f[c];
        Hi[c] = bf_rne(a);
        Lo[c] = bf_rne(a - bf_to_f(Hi[c]));
    }
    float mi = -0.5f * C_LOG2E * s;
    mhs[i] = mi;
    ushort mih = bf_rne(mi);
    ushort mil = bf_rne(mi - bf_to_f(mih));
    {   // A-side row: [h0..h4, l2,l3,l4, h2,h3,h4, l2,l3,l4, 1.0, 1.0]
        ushort r0[16] = { hi[0], hi[1], hi[2], hi[3], hi[4], lo[2], lo[3], lo[4],
                          hi[2], hi[3], hi[4], lo[2], lo[3], lo[4], 0x3F80, 0x3F80 };
        uint4 w0, w1;
        w0.x = (uint)r0[0] | ((uint)r0[1] << 16);  w0.y = (uint)r0[2] | ((uint)r0[3] << 16);
        w0.z = (uint)r0[4] | ((uint)r0[5] << 16);  w0.w = (uint)r0[6] | ((uint)r0[7] << 16);
        w1.x = (uint)r0[8] | ((uint)r0[9] << 16);  w1.y = (uint)r0[10] | ((uint)r0[11] << 16);
        w1.z = (uint)r0[12] | ((uint)r0[13] << 16); w1.w = (uint)r0[14] | ((uint)r0[15] << 16);
        *(uint4*)(fjg + (size_t)i * 16) = w0;
        *(uint4*)(fjg + (size_t)i * 16 + 8) = w1;
    }
    {   // B-side row: [H0..H4, H2,H3,H4, L2,L3,L4, L2,L3,L4, mih, mil]
        ushort r1[16] = { Hi[0], Hi[1], Hi[2], Hi[3], Hi[4], Hi[2], Hi[3], Hi[4],
                          Lo[2], Lo[3], Lo[4], Lo[2], Lo[3], Lo[4], mih, mil };
        uint4 w0, w1;
        w0.x = (uint)r1[0] | ((uint)r1[1] << 16);  w0.y = (uint)r1[2] | ((uint)r1[3] << 16);
        w0.z = (uint)r1[4] | ((uint)r1[5] << 16);  w0.w = (uint)r1[6] | ((uint)r1[7] << 16);
        w1.x = (uint)r1[8] | ((uint)r1[9] << 16);  w1.y = (uint)r1[10] | ((uint)r1[11] << 16);
        w1.z = (uint)r1[12] | ((uint)r1[13] << 16); w1.w = (uint)r1[14] | ((uint)r1[15] << 16);
        *(uint4*)(fig + (size_t)i * 8) = w0;
        *(uint4*)(fig + (size_t)i * 8 + 4) = w1;
    }
    nsp[i] = 1.0f / (sxT[x] * sxT[y] + 1e-8f);
    float v[LL];
    float mx = -1e30f;
    for (int l = 0; l < LL; l++) { v[l] = unary[l * NPIX + i]; mx = fmaxf(mx, v[l]); }
    float ss = 0.f;
    for (int l = 0; l < LL; l++) { v[l] = __expf(v[l] - mx); ss += v[l]; }
    float r = 1.0f / ss;
    for (int l = 0; l < LL; l++) qb16[(size_t)l * NPIX + i] = bf_rne(v[l] * r);
}

__device__ inline f32x16 ldmhs(const float* p, int h) {
    float4 a0 = *(const float4*)(p + 8 * h);
    float4 a1 = *(const float4*)(p + 8 * h + 4);
    float4 a2 = *(const float4*)(p + 16 + 8 * h);
    float4 a3 = *(const float4*)(p + 16 + 8 * h + 4);
    f32x16 cv;
    cv[0] = a0.x;  cv[1] = a0.y;  cv[2] = a0.z;  cv[3] = a0.w;
    cv[4] = a1.x;  cv[5] = a1.y;  cv[6] = a1.z;  cv[7] = a1.w;
    cv[8] = a2.x;  cv[9] = a2.y;  cv[10] = a2.z; cv[11] = a2.w;
    cv[12] = a3.x; cv[13] = a3.y; cv[14] = a3.z; cv[15] = a3.w;
    return cv;
}

// ================ iteration kernel 1: 1000 blocks, one co-residency round.
// bilat MFMA tile; bip partials packed bf16x2 (rows l,l+1 per u32, 11 rows).
// Uniform ~134-px spat_x rider (reads qb16).
__global__ __launch_bounds__(256, 4)
void k_iter1(const float* __restrict__ mhs, const ushort* __restrict__ fjg,
             const uint* __restrict__ fig, const ushort* __restrict__ qb16,
             uint* __restrict__ bip, float* __restrict__ tmpx) {
    __shared__ __align__(16) uint  FjL[SJ * 12];
    __shared__ __align__(16) float mhsL[SJ];
    __shared__ __align__(16) uint  QL[QROWS * QROW];
    __shared__ float gT[WW];
    int tid = threadIdx.x;
    int bid = blockIdx.x;
    int bx = bid % 50, by = bid / 50;
    int j0 = by * SJ;
    // ---- stage Q first (most global-load latency to hide)
    for (int idx = tid; idx < QROWS * (SJ / 2); idx += 256) {
        int l = idx / (SJ / 2), jp = idx % (SJ / 2);
        uint v;
        if (l < LL) {
            const uint* p = (const uint*)qb16 + (((size_t)l * NPIX + j0) >> 1);
            v = p[jp];
        } else {
            v = 0x3F803F80u;
        }
        QL[l * QROW + jp] = v;
    }
    for (int idx = tid; idx < SJ * 2; idx += 256) {
        int r = idx >> 1, hf = idx & 1;
        uint4 v = ((const uint4*)(fjg + (size_t)(j0 + r) * 16))[hf];
        *(uint4*)&FjL[r * 12 + hf * 4] = v;
    }
    for (int idx = tid; idx < SJ; idx += 256) mhsL[idx] = mhs[j0 + idx];
    if (tid < WW) gT[tid] = __expf(-(float)(tid * tid) * (1.0f / 18.0f));
    int lane = tid & 63, wid = tid >> 6;
    int h = lane >> 5, m = lane & 31;
    int i = bx * 128 + wid * 32 + m;
    union U8 { uint u[4]; short8 s; };
    U8 bfr;
    {
        uint4 bv = *(const uint4*)(fig + (size_t)i * 8 + h * 4);
        bfr.u[0] = bv.x; bfr.u[1] = bv.y; bfr.u[2] = bv.z; bfr.u[3] = bv.w;
    }
    int jrow = (m & ~12) | ((m & 4) << 1) | ((m & 8) >> 1);
    int qrow = (m < QROWS) ? m : 0;
    __syncthreads();
    f32x16 acc;
#pragma unroll
    for (int k = 0; k < 16; k++) acc[k] = 0.f;
    const uint* qbase = &QL[qrow * QROW + h * 4];
    for (int c = 0; c < CHK; c++) {
        int jb = c * 32;
        f32x16 cv = ldmhs(&mhsL[jb], h);
        short8 af = *(const short8*)&FjL[(jb + jrow) * 12 + h * 4];
        f32x16 d1 = __builtin_amdgcn_mfma_f32_32x32x16_bf16(af, bfr.s, cv, 0, 0, 0);
        short8 qa = *(const short8*)(qbase + c * 16);
        short8 qb = *(const short8*)(qbase + c * 16 + 8);
        U8 ea;
        ea.u[0] = pk2z(fexp2(d1[0]), fexp2(d1[1]));
        ea.u[1] = pk2z(fexp2(d1[2]), fexp2(d1[3]));
        ea.u[2] = pk2z(fexp2(d1[4]), fexp2(d1[5]));
        ea.u[3] = pk2z(fexp2(d1[6]), fexp2(d1[7]));
        acc = __builtin_amdgcn_mfma_f32_32x32x16_bf16(qa, ea.s, acc, 0, 0, 0);
        U8 eb;
        eb.u[0] = pk2z(fexp2(d1[8]),  fexp2(d1[9]));
        eb.u[1] = pk2z(fexp2(d1[10]), fexp2(d1[11]));
        eb.u[2] = pk2z(fexp2(d1[12]), fexp2(d1[13]));
        eb.u[3] = pk2z(fexp2(d1[14]), fexp2(d1[15]));
        acc = __builtin_amdgcn_mfma_f32_32x32x16_bf16(qb, eb.s, acc, 0, 0, 0);
    }
    // ---- epilogue: pack adjacent-l pairs (C-layout gives l, l+1 at regs r, r+1
    // for even r) into bf16x2; rows 0..21 -> row-pairs 0..10, skip l >= 22.
#pragma unroll
    for (int r = 0; r < 16; r += 2) {
        int l = (r & 3) + 8 * (r >> 2) + 4 * h;    // even l of the pair
        if (l < LL + 1)
            bip[((size_t)by * NLP + (l >> 1)) * NPIX + i] = pk2(acc[r], acc[r + 1]);
    }
    // ---- spat_x rider: uniform ~134-px slice; reads bf16 Q
    {
        int start = (int)(((long)bid * SPWORK) / NBLK);
        int end   = (int)(((long)(bid + 1) * SPWORK) / NBLK);
        int cnt = end - start;
        if (tid < cnt) {
            int fidx = start + tid;
            int l = fidx / NPIX;
            int p = fidx - l * NPIX;
            int x = p % WW, y = p / WW;
            const ushort* rowq = qb16 + (size_t)l * NPIX + y * WW;
            float s = 0.f;
            for (int xp = 0; xp < WW; xp++) {
                int d = x - xp; d = d < 0 ? -d : d;
                s += gT[d] * bf_to_f(rowq[xp]);
            }
            tmpx[(size_t)l * NPIX + p] = s;
        }
    }
}

// ================ iteration kernel 2 (merged): spat_y + reduce + combine + softmax
// 400 blocks x 384 thr; block owns ALL rows of its 16 pixels.
// Phase A1: 336 spat_y tasks; Phase A2: 176 packed-reduce tasks (no barrier
// between — disjoint LDS arrays).
__global__ __launch_bounds__(SYT)
void k_syc(const float* __restrict__ unary, const float* __restrict__ tmpx,
           const uint* __restrict__ bip, const float* __restrict__ nsp,
           const float* __restrict__ M1, const float* __restrict__ M2,
           ushort* __restrict__ qb16, float* __restrict__ out, int last) {
    __shared__ float m1s[LL * 24];
    __shared__ float m2s[LL * 24];
    __shared__ float gT[HH];
    __shared__ float svL[PXB][QROWS];   // [pxl][l] spatial (l<21)
    __shared__ float bvL[PXB][QROWS];   // [pxl][l] bilat reduce (l<=21)
    __shared__ float aex[PXB][QROWS];   // [pxl][l] combined logits
    int tid = threadIdx.x;
    int px0 = blockIdx.x * PXB;
    for (int t = tid; t < LL * LL; t += SYT) {
        int l = t / LL, k = t % LL;
        m1s[l * 24 + k] = M1[t];
        m2s[l * 24 + k] = M2[t];
    }
    if (tid < HH) gT[tid] = __expf(-(float)(tid * tid) * (1.0f / 18.0f));
    __syncthreads();
    // ---- phase A1: spat_y conv, 16 px x 21 labels = 336 tasks
    if (tid < PXB * LL) {
        int pxl = tid & (PXB - 1);
        int l = tid >> 4;
        int px = px0 + pxl;
        int x = px % WW, y = px / WW;
        const float* base = tmpx + (size_t)l * NPIX + x;
        float s1 = 0.f;
        for (int yp = 0; yp < HH; yp++) {
            int d = y - yp; d = d < 0 ? -d : d;
            s1 += gT[d] * base[yp * WW];
        }
        svL[pxl][l] = s1;
    }
    // ---- phase A2: packed bip reduce, 16 px x 11 row-pairs = 176 tasks
    if (tid < PXB * NLP) {
        int pxl = tid & (PXB - 1);
        int lp = tid >> 4;
        int px = px0 + pxl;
        float sa = 0.f, sb = 0.f;
        const uint* p = bip + (size_t)lp * NPIX + px;
#pragma unroll
        for (int byi = 0; byi < NBY; byi++) {
            uint v = p[(size_t)byi * NLP * NPIX];
            sa += __uint_as_float(v << 16);
            sb += __uint_as_float(v & 0xFFFF0000u);
        }
        bvL[pxl][2 * lp] = sa;
        bvL[pxl][2 * lp + 1] = sb;
    }
    __syncthreads();
    // ---- phase B1: combine  a[l] = unary + ns*(M1.sv) + nb*(M2.bv)
    if (tid < PXB * LL) {
        int pxl = tid & (PXB - 1);
        int l = tid >> 4;             // 0..20
        int px = px0 + pxl;
        float ns = nsp[px];
        float nb = 1.0f / (bvL[pxl][LL] + 1e-8f);
        float s1 = 0.f, s2 = 0.f;
        const float* r1 = &m1s[l * 24];
        const float* r2 = &m2s[l * 24];
#pragma unroll
        for (int k = 0; k < LL; k++) {
            s1 = fmaf(r1[k], svL[pxl][k], s1);
            s2 = fmaf(r2[k], bvL[pxl][k], s2);
        }
        float a = unary[l * NPIX + px] + ns * s1 + nb * s2;
        if (last) out[(size_t)l * NPIX + px] = a;
        else      aex[pxl][l] = a;
    }
    if (last) return;
    __syncthreads();
    // ---- phase B2: per-pixel softmax -> qb16
    if (tid < PXB) {
        int px = px0 + tid;
        float mx = -1e30f;
        for (int l = 0; l < LL; l++) mx = fmaxf(mx, aex[tid][l]);
        float s = 0.f;
        float e[LL];
        for (int l = 0; l < LL; l++) { e[l] = __expf(aex[tid][l] - mx); s += e[l]; }
        float r = 1.0f / s;
        for (int l = 0; l < LL; l++)
            qb16[(size_t)l * NPIX + px] = bf_rne(e[l] * r);
    }
}

extern "C" void kernel_launch(void* const* d_in, const int* in_sizes, int n_in,
                              void* d_out, int out_size, void* d_ws, size_t ws_size,
                              hipStream_t stream) {
    const float* img   = (const float*)d_in[0];
    const float* unary = (const float*)d_in[1];
    const float* Wsp   = (const float*)d_in[2];
    const float* Wbi   = (const float*)d_in[3];
    const float* C     = (const float*)d_in[4];
    float* out = (float*)d_out;

    const int LN = LL * NPIX;
    float* w = (float*)d_ws;
    float*  tmpx = w;  w += LN;
    uint*   bip  = (uint*)w;    w += NBY * NLP * NPIX;  // packed bf16x2 partials
    float*  mhs  = w;  w += NPIX;
    float*  nsp  = w;  w += NPIX;
    ushort* fjg  = (ushort*)w;  w += 8 * NPIX;        // A-rows [N][16 bf16]
    uint*   fig  = (uint*)w;    w += 8 * NPIX;        // B-rows [N][8 u32]
    ushort* qb16 = (ushort*)w;  w += (LN + 1) / 2;    // Q in bf16 [21][N]
    float*  M1   = w;  w += LL * LL;
    float*  M2   = w;  w += LL * LL;

    k_setup<<<26, 256, 0, stream>>>(img, unary, Wsp, Wbi, C, fjg, fig, mhs, nsp,
                                    qb16, M1, M2);
    for (int it = 0; it < NITER; it++) {
        int last = (it == NITER - 1);
        k_iter1<<<NBLK, 256, 0, stream>>>(mhs, fjg, fig, qb16, bip, tmpx);
        k_syc<<<SYB, SYT, 0, stream>>>(unary, tmpx, bip, nsp, M1, M2, qb16, out, last);
    }
}